// Round 1
// baseline (1291.758 us; speedup 1.0000x reference)
//
#include <hip/hip_runtime.h>

// Problem constants (from reference setup_inputs)
#define NC    32           // channels
#define NH1   256          // hidden dim
#define W_YX  727
#define H_YX  314
#define W_ZX  727
#define H_ZX  1300
#define W_ZY  314
#define H_ZY  1300
#define HW_YX (W_YX * H_YX)   // 228278
#define HW_ZX (W_ZX * H_ZX)   // 945100
#define HW_ZY (W_ZY * H_ZY)   // 408200

// ---------------------------------------------------------------------------
// Transpose one plane (C=32, HW) -> (HW, C=32) so channels are contiguous.
// 32x32 tile via LDS, +1 pad to kill bank conflicts.
// ---------------------------------------------------------------------------
__global__ __launch_bounds__(256) void kplane_transpose(
    const float* __restrict__ src, float* __restrict__ dst, int HW)
{
    __shared__ float tile[32][33];
    int hw0 = blockIdx.x * 32;
    int tx = threadIdx.x & 31;   // fast index
    int ty = threadIdx.x >> 5;   // 0..7
#pragma unroll
    for (int i = 0; i < 4; ++i) {
        int c  = ty + i * 8;          // channel row
        int hw = hw0 + tx;
        tile[c][tx] = (hw < HW) ? src[(size_t)c * HW + hw] : 0.0f;
    }
    __syncthreads();
#pragma unroll
    for (int i = 0; i < 4; ++i) {
        int r  = ty + i * 8;          // local hw
        int hw = hw0 + r;
        if (hw < HW) dst[(size_t)hw * NC + tx] = tile[tx][r];
    }
}

// ---------------------------------------------------------------------------
// Bilinear setup: replicates reference align_corners=True convention exactly.
// ---------------------------------------------------------------------------
__device__ __forceinline__ void bilin(
    float gx, float gy, int W, int H,
    int& o00, int& o01, int& o10, int& o11,
    float& w00, float& w01, float& w10, float& w11)
{
    float ix  = (gx + 1.0f) * 0.5f * (float)(W - 1);
    float iy  = (gy + 1.0f) * 0.5f * (float)(H - 1);
    float x0f = floorf(ix), y0f = floorf(iy);
    float wx  = ix - x0f,   wy  = iy - y0f;
    int x0 = (int)x0f; x0 = x0 < 0 ? 0 : (x0 > W - 1 ? W - 1 : x0);
    int y0 = (int)y0f; y0 = y0 < 0 ? 0 : (y0 > H - 1 ? H - 1 : y0);
    int x1 = x0 + 1; if (x1 > W - 1) x1 = W - 1;
    int y1 = y0 + 1; if (y1 > H - 1) y1 = H - 1;
    o00 = y0 * W + x0; o01 = y0 * W + x1;
    o10 = y1 * W + x0; o11 = y1 * W + x1;
    w00 = (1.0f - wx) * (1.0f - wy);
    w01 = wx * (1.0f - wy);
    w10 = (1.0f - wx) * wy;
    w11 = wx * wy;
}

// Sample 32 channels from a channel-contiguous plane; FIRST writes feat,
// otherwise multiplies into feat (the tri-plane product).
template <bool FIRST>
__device__ __forceinline__ void sample_mul(
    const float* __restrict__ t,
    int b00, int b01, int b10, int b11,
    float w00, float w01, float w10, float w11,
    float feat[NC])
{
    const float4* __restrict__ p00 = reinterpret_cast<const float4*>(t + b00);
    const float4* __restrict__ p01 = reinterpret_cast<const float4*>(t + b01);
    const float4* __restrict__ p10 = reinterpret_cast<const float4*>(t + b10);
    const float4* __restrict__ p11 = reinterpret_cast<const float4*>(t + b11);
#pragma unroll
    for (int q = 0; q < 8; ++q) {
        float4 a = p00[q], b = p01[q], c = p10[q], d = p11[q];
        float sx = w00 * a.x + w01 * b.x + w10 * c.x + w11 * d.x;
        float sy = w00 * a.y + w01 * b.y + w10 * c.y + w11 * d.y;
        float sz = w00 * a.z + w01 * b.z + w10 * c.z + w11 * d.z;
        float sw = w00 * a.w + w01 * b.w + w10 * c.w + w11 * d.w;
        if (FIRST) {
            feat[4 * q + 0] = sx; feat[4 * q + 1] = sy;
            feat[4 * q + 2] = sz; feat[4 * q + 3] = sw;
        } else {
            feat[4 * q + 0] *= sx; feat[4 * q + 1] *= sy;
            feat[4 * q + 2] *= sz; feat[4 * q + 3] *= sw;
        }
    }
}

// Shared MLP epilogue. w1 is (C=32, 256) row-major; w2 is (256, 4).
// All weight indices are wave-uniform -> compiler emits s_load + SGPR-operand
// v_fma (no per-lane weight traffic).
__device__ __forceinline__ void mlp_and_store(
    const float feat[NC],
    const float* __restrict__ w1, const float* __restrict__ b1,
    const float* __restrict__ w2, const float* __restrict__ b2,
    float* __restrict__ out, int i)
{
    float o0 = b2[0], o1 = b2[1], o2 = b2[2], o3 = b2[3];
#pragma unroll 4
    for (int k = 0; k < NH1; ++k) {
        float hk = b1[k];
#pragma unroll
        for (int c = 0; c < NC; ++c)
            hk = fmaf(feat[c], w1[c * NH1 + k], hk);
        hk = fmaxf(hk, 0.0f);
        o0 = fmaf(hk, w2[k * 4 + 0], o0);
        o1 = fmaf(hk, w2[k * 4 + 1], o1);
        o2 = fmaf(hk, w2[k * 4 + 2], o2);
        o3 = fmaf(hk, w2[k * 4 + 3], o3);
    }
    float4 o; o.x = o0; o.y = o1; o.z = o2; o.w = o3;
    reinterpret_cast<float4*>(out)[i] = o;
}

// ---------------------------------------------------------------------------
// Fast path: gather from channel-contiguous (transposed) planes in d_ws.
// ---------------------------------------------------------------------------
__global__ __launch_bounds__(256) void kplane_fused_t(
    const float* __restrict__ pts,
    const float* __restrict__ tyx, const float* __restrict__ tzx,
    const float* __restrict__ tzy,
    const float* __restrict__ w1, const float* __restrict__ b1,
    const float* __restrict__ w2, const float* __restrict__ b2,
    float* __restrict__ out, int N)
{
    int i = blockIdx.x * blockDim.x + threadIdx.x;
    if (i >= N) return;
    float px = pts[(size_t)i * 3 + 0];
    float py = pts[(size_t)i * 3 + 1];
    float pz = pts[(size_t)i * 3 + 2];

    float feat[NC];
    int o00, o01, o10, o11; float w00, w01, w10, w11;

    // plane_yx: gx=px (W=727), gy=py (H=314)
    bilin(px, py, W_YX, H_YX, o00, o01, o10, o11, w00, w01, w10, w11);
    sample_mul<true >(tyx, o00 * NC, o01 * NC, o10 * NC, o11 * NC,
                      w00, w01, w10, w11, feat);
    // plane_zx: gx=px (W=727), gy=pz (H=1300)
    bilin(px, pz, W_ZX, H_ZX, o00, o01, o10, o11, w00, w01, w10, w11);
    sample_mul<false>(tzx, o00 * NC, o01 * NC, o10 * NC, o11 * NC,
                      w00, w01, w10, w11, feat);
    // plane_zy: gx=py (W=314), gy=pz (H=1300)
    bilin(py, pz, W_ZY, H_ZY, o00, o01, o10, o11, w00, w01, w10, w11);
    sample_mul<false>(tzy, o00 * NC, o01 * NC, o10 * NC, o11 * NC,
                      w00, w01, w10, w11, feat);

    mlp_and_store(feat, w1, b1, w2, b2, out, i);
}

// ---------------------------------------------------------------------------
// Fallback path (ws too small): gather directly from (C,H,W) layout.
// ---------------------------------------------------------------------------
__global__ __launch_bounds__(256) void kplane_fused_direct(
    const float* __restrict__ pts,
    const float* __restrict__ pyx, const float* __restrict__ pzx,
    const float* __restrict__ pzy,
    const float* __restrict__ w1, const float* __restrict__ b1,
    const float* __restrict__ w2, const float* __restrict__ b2,
    float* __restrict__ out, int N)
{
    int i = blockIdx.x * blockDim.x + threadIdx.x;
    if (i >= N) return;
    float px = pts[(size_t)i * 3 + 0];
    float py = pts[(size_t)i * 3 + 1];
    float pz = pts[(size_t)i * 3 + 2];

    int a00, a01, a10, a11; float aw00, aw01, aw10, aw11;
    int c00, c01, c10, c11; float cw00, cw01, cw10, cw11;
    int d00, d01, d10, d11; float dw00, dw01, dw10, dw11;
    bilin(px, py, W_YX, H_YX, a00, a01, a10, a11, aw00, aw01, aw10, aw11);
    bilin(px, pz, W_ZX, H_ZX, c00, c01, c10, c11, cw00, cw01, cw10, cw11);
    bilin(py, pz, W_ZY, H_ZY, d00, d01, d10, d11, dw00, dw01, dw10, dw11);

    float feat[NC];
#pragma unroll 4
    for (int c = 0; c < NC; ++c) {
        const float* byx = pyx + (size_t)c * HW_YX;
        const float* bzx = pzx + (size_t)c * HW_ZX;
        const float* bzy = pzy + (size_t)c * HW_ZY;
        float fyx = aw00 * byx[a00] + aw01 * byx[a01] + aw10 * byx[a10] + aw11 * byx[a11];
        float fzx = cw00 * bzx[c00] + cw01 * bzx[c01] + cw10 * bzx[c10] + cw11 * bzx[c11];
        float fzy = dw00 * bzy[d00] + dw01 * bzy[d01] + dw10 * bzy[d10] + dw11 * bzy[d11];
        feat[c] = fyx * fzx * fzy;
    }
    mlp_and_store(feat, w1, b1, w2, b2, out, i);
}

// ---------------------------------------------------------------------------
extern "C" void kernel_launch(void* const* d_in, const int* in_sizes, int n_in,
                              void* d_out, int out_size, void* d_ws, size_t ws_size,
                              hipStream_t stream)
{
    const float* pts = (const float*)d_in[0];
    const float* pyx = (const float*)d_in[1];
    const float* pzx = (const float*)d_in[2];
    const float* pzy = (const float*)d_in[3];
    const float* w1  = (const float*)d_in[4];
    const float* b1  = (const float*)d_in[5];
    const float* w2  = (const float*)d_in[6];
    const float* b2  = (const float*)d_in[7];
    float* out = (float*)d_out;

    int N = in_sizes[0] / 3;
    int blocks = (N + 255) / 256;

    size_t need = (size_t)(HW_YX + HW_ZX + HW_ZY) * NC * sizeof(float); // 202.4 MB

    if (ws_size >= need) {
        float* tyx = (float*)d_ws;
        float* tzx = tyx + (size_t)HW_YX * NC;
        float* tzy = tzx + (size_t)HW_ZX * NC;
        kplane_transpose<<<(HW_YX + 31) / 32, 256, 0, stream>>>(pyx, tyx, HW_YX);
        kplane_transpose<<<(HW_ZX + 31) / 32, 256, 0, stream>>>(pzx, tzx, HW_ZX);
        kplane_transpose<<<(HW_ZY + 31) / 32, 256, 0, stream>>>(pzy, tzy, HW_ZY);
        kplane_fused_t<<<blocks, 256, 0, stream>>>(pts, tyx, tzx, tzy,
                                                   w1, b1, w2, b2, out, N);
    } else {
        kplane_fused_direct<<<blocks, 256, 0, stream>>>(pts, pyx, pzx, pzy,
                                                        w1, b1, w2, b2, out, N);
    }
}

// Round 2
// 782.966 us; speedup vs baseline: 1.6498x; 1.6498x over previous
//
#include <hip/hip_runtime.h>

// Problem constants (from reference setup_inputs)
#define NC    32           // channels
#define NH1   256          // hidden dim
#define W_YX  727
#define H_YX  314
#define W_ZX  727
#define H_ZX  1300
#define W_ZY  314
#define H_ZY  1300
#define HW_YX (W_YX * H_YX)   // 228278
#define HW_ZX (W_ZX * H_ZX)   // 945100
#define HW_ZY (W_ZY * H_ZY)   // 408200

typedef __attribute__((ext_vector_type(8))) short short8;   // 8 bf16 (4 VGPRs)
typedef __attribute__((ext_vector_type(4))) float f32x4;    // MFMA acc

// float -> bf16 (RNE) and back, as raw shorts
__device__ __forceinline__ short f2bf(float f) {
    unsigned u = __float_as_uint(f);
    unsigned r = u + 0x7fffu + ((u >> 16) & 1u);
    return (short)(r >> 16);
}
__device__ __forceinline__ float bf2f(short s) {
    return __uint_as_float(((unsigned)(unsigned short)s) << 16);
}

// ---------------------------------------------------------------------------
// Transpose (C=32, HW) -> (HW, C=32), float4 both directions.
// 32ch x 128hw tile per block; stores are 1KB-contiguous per wave instr.
// ---------------------------------------------------------------------------
__global__ __launch_bounds__(256) void kplane_transpose4(
    const float* __restrict__ src, float* __restrict__ dst, int HW)
{
    __shared__ float tile[32][129];
    int hw0 = blockIdx.x * 128;
    int tx = threadIdx.x & 31, ty = threadIdx.x >> 5;
    if (hw0 + 128 <= HW) {
#pragma unroll
        for (int i = 0; i < 4; ++i) {
            int c = ty + i * 8;
            float4 v = *(const float4*)(src + (size_t)c * HW + hw0 + tx * 4);
            tile[c][tx * 4 + 0] = v.x; tile[c][tx * 4 + 1] = v.y;
            tile[c][tx * 4 + 2] = v.z; tile[c][tx * 4 + 3] = v.w;
        }
    } else {
        for (int i = 0; i < 4; ++i) {
            int c = ty + i * 8;
            for (int e = 0; e < 4; ++e) {
                int hw = hw0 + tx * 4 + e;
                tile[c][tx * 4 + e] = (hw < HW) ? src[(size_t)c * HW + hw] : 0.0f;
            }
        }
    }
    __syncthreads();
    int c4 = threadIdx.x & 7, r0 = threadIdx.x >> 3;
#pragma unroll
    for (int i = 0; i < 4; ++i) {
        int r = r0 + i * 32;
        int hw = hw0 + r;
        if (hw < HW) {
            float4 o;
            o.x = tile[c4 * 4 + 0][r]; o.y = tile[c4 * 4 + 1][r];
            o.z = tile[c4 * 4 + 2][r]; o.w = tile[c4 * 4 + 3][r];
            *(float4*)(dst + (size_t)hw * NC + c4 * 4) = o;
        }
    }
}

// ---------------------------------------------------------------------------
// Precompute w1 (32x256 fp32) as bf16 hi/lo in B-fragment order:
// idx = (ntile*64 + lane)*8 + j holds B[k=(lane>>4)*8+j][n=ntile*16+(lane&15)]
// ---------------------------------------------------------------------------
__global__ __launch_bounds__(256) void kplane_prep_w1(
    const float* __restrict__ w1, short* __restrict__ whi, short* __restrict__ wlo)
{
    int idx = blockIdx.x * 256 + threadIdx.x;   // 0..8191
    int jj   = idx & 7;
    int lane = (idx >> 3) & 63;
    int nt   = idx >> 9;
    int n = nt * 16 + (lane & 15);
    int k = (lane >> 4) * 8 + jj;
    float wv = w1[k * NH1 + n];
    short hi = f2bf(wv);
    float rem = wv - bf2f(hi);
    whi[idx] = hi;
    wlo[idx] = f2bf(rem);
}

// ---------------------------------------------------------------------------
// Bilinear setup (align_corners=True, identical to reference).
// ---------------------------------------------------------------------------
__device__ __forceinline__ void bilin(
    float gx, float gy, int W, int H,
    int& o00, int& o01, int& o10, int& o11,
    float& w00, float& w01, float& w10, float& w11)
{
    float ix  = (gx + 1.0f) * 0.5f * (float)(W - 1);
    float iy  = (gy + 1.0f) * 0.5f * (float)(H - 1);
    float x0f = floorf(ix), y0f = floorf(iy);
    float wx  = ix - x0f,   wy  = iy - y0f;
    int x0 = (int)x0f; x0 = x0 < 0 ? 0 : (x0 > W - 1 ? W - 1 : x0);
    int y0 = (int)y0f; y0 = y0 < 0 ? 0 : (y0 > H - 1 ? H - 1 : y0);
    int x1 = x0 + 1; if (x1 > W - 1) x1 = W - 1;
    int y1 = y0 + 1; if (y1 > H - 1) y1 = H - 1;
    o00 = y0 * W + x0; o01 = y0 * W + x1;
    o10 = y1 * W + x0; o11 = y1 * W + x1;
    w00 = (1.0f - wx) * (1.0f - wy);
    w01 = wx * (1.0f - wy);
    w10 = (1.0f - wx) * wy;
    w11 = wx * wy;
}

// ---------------------------------------------------------------------------
// Fused kernel: cooperative gather (8 lanes/point, coalesced 128B corners)
// + MFMA MLP (bf16x3 split for fp32-grade accuracy).
// Block = 256 threads = 256 points. Requires N % 256 == 0.
// ---------------------------------------------------------------------------
__global__ __launch_bounds__(256) void kplane_mfma(
    const float* __restrict__ pts,
    const float* __restrict__ tyx, const float* __restrict__ tzx,
    const float* __restrict__ tzy,
    const short* __restrict__ w1hi, const short* __restrict__ w1lo,
    const float* __restrict__ b1, const float* __restrict__ w2,
    const float* __restrict__ b2,
    float* __restrict__ out)
{
    __shared__ float ptsS[256 * 3];
    __shared__ float featS[256 * 36];   // stride 36 to de-phase banks

    int t = threadIdx.x;
    int base = blockIdx.x * 256;

    // ---- phase 0: stage this block's points -------------------------------
    {
        int p = base + t;
        ptsS[t * 3 + 0] = pts[(size_t)p * 3 + 0];
        ptsS[t * 3 + 1] = pts[(size_t)p * 3 + 1];
        ptsS[t * 3 + 2] = pts[(size_t)p * 3 + 2];
    }
    __syncthreads();

    // ---- phase 1: cooperative tri-plane gather ----------------------------
    {
        int g = t >> 3, j = t & 7;      // 8 lanes per point
        const float4* Tyx = (const float4*)tyx;
        const float4* Tzx = (const float4*)tzx;
        const float4* Tzy = (const float4*)tzy;
        for (int r = 0; r < 8; ++r) {
            int p = g * 8 + r;          // local point id
            float px = ptsS[p * 3 + 0];
            float py = ptsS[p * 3 + 1];
            float pz = ptsS[p * 3 + 2];

            int a0,a1,a2,a3,c0,c1,c2,c3,d0,d1,d2,d3;
            float aw0,aw1,aw2,aw3,cw0,cw1,cw2,cw3,dw0,dw1,dw2,dw3;
            bilin(px, py, W_YX, H_YX, a0,a1,a2,a3, aw0,aw1,aw2,aw3);
            bilin(px, pz, W_ZX, H_ZX, c0,c1,c2,c3, cw0,cw1,cw2,cw3);
            bilin(py, pz, W_ZY, H_ZY, d0,d1,d2,d3, dw0,dw1,dw2,dw3);

            // 12 independent, group-coalesced 16B loads (each corner = 128B line)
            float4 va0 = Tyx[a0 * 8 + j], va1 = Tyx[a1 * 8 + j];
            float4 va2 = Tyx[a2 * 8 + j], va3 = Tyx[a3 * 8 + j];
            float4 vc0 = Tzx[c0 * 8 + j], vc1 = Tzx[c1 * 8 + j];
            float4 vc2 = Tzx[c2 * 8 + j], vc3 = Tzx[c3 * 8 + j];
            float4 vd0 = Tzy[d0 * 8 + j], vd1 = Tzy[d1 * 8 + j];
            float4 vd2 = Tzy[d2 * 8 + j], vd3 = Tzy[d3 * 8 + j];

            float4 fa, fc, fd, f;
            fa.x = aw0*va0.x + aw1*va1.x + aw2*va2.x + aw3*va3.x;
            fa.y = aw0*va0.y + aw1*va1.y + aw2*va2.y + aw3*va3.y;
            fa.z = aw0*va0.z + aw1*va1.z + aw2*va2.z + aw3*va3.z;
            fa.w = aw0*va0.w + aw1*va1.w + aw2*va2.w + aw3*va3.w;
            fc.x = cw0*vc0.x + cw1*vc1.x + cw2*vc2.x + cw3*vc3.x;
            fc.y = cw0*vc0.y + cw1*vc1.y + cw2*vc2.y + cw3*vc3.y;
            fc.z = cw0*vc0.z + cw1*vc1.z + cw2*vc2.z + cw3*vc3.z;
            fc.w = cw0*vc0.w + cw1*vc1.w + cw2*vc2.w + cw3*vc3.w;
            fd.x = dw0*vd0.x + dw1*vd1.x + dw2*vd2.x + dw3*vd3.x;
            fd.y = dw0*vd0.y + dw1*vd1.y + dw2*vd2.y + dw3*vd3.y;
            fd.z = dw0*vd0.z + dw1*vd1.z + dw2*vd2.z + dw3*vd3.z;
            fd.w = dw0*vd0.w + dw1*vd1.w + dw2*vd2.w + dw3*vd3.w;
            f.x = fa.x * fc.x * fd.x;
            f.y = fa.y * fc.y * fd.y;
            f.z = fa.z * fc.z * fd.z;
            f.w = fa.w * fc.w * fd.w;
            *(float4*)(&featS[p * 36 + j * 4]) = f;
        }
    }
    __syncthreads();

    // ---- phase 2: MFMA MLP -------------------------------------------------
    {
        int lane = t & 63, w = t >> 6;
        int quad = lane >> 4, l15 = lane & 15;
        float4 b2v = *(const float4*)b2;
        const short8* Bhi = (const short8*)w1hi;
        const short8* Blo = (const short8*)w1lo;

#pragma unroll
        for (int mt = 0; mt < 4; ++mt) {
            int ptLocal = w * 64 + mt * 16 + l15;
            const float* fr = &featS[ptLocal * 36 + quad * 8];
            float4 f0 = *(const float4*)(fr);
            float4 f1 = *(const float4*)(fr + 4);

            float av[8] = {f0.x, f0.y, f0.z, f0.w, f1.x, f1.y, f1.z, f1.w};
            short8 ahi, alo;
#pragma unroll
            for (int e = 0; e < 8; ++e) {
                short h = f2bf(av[e]);
                ahi[e] = h;
                alo[e] = f2bf(av[e] - bf2f(h));
            }

            float4 oo0 = {0,0,0,0}, oo1 = {0,0,0,0}, oo2 = {0,0,0,0}, oo3 = {0,0,0,0};
#pragma unroll
            for (int nt = 0; nt < 16; ++nt) {
                short8 bh = Bhi[nt * 64 + lane];
                short8 bl = Blo[nt * 64 + lane];
                f32x4 z = {0.f, 0.f, 0.f, 0.f};
                z = __builtin_amdgcn_mfma_f32_16x16x32_bf16(alo, bh, z, 0, 0, 0);
                z = __builtin_amdgcn_mfma_f32_16x16x32_bf16(ahi, bl, z, 0, 0, 0);
                z = __builtin_amdgcn_mfma_f32_16x16x32_bf16(ahi, bh, z, 0, 0, 0);
                float  b1v = b1[nt * 16 + l15];
                float4 w2v = ((const float4*)w2)[nt * 16 + l15];
                float h0 = fmaxf(z[0] + b1v, 0.f);
                float h1 = fmaxf(z[1] + b1v, 0.f);
                float h2 = fmaxf(z[2] + b1v, 0.f);
                float h3 = fmaxf(z[3] + b1v, 0.f);
                oo0.x = fmaf(h0, w2v.x, oo0.x); oo0.y = fmaf(h0, w2v.y, oo0.y);
                oo0.z = fmaf(h0, w2v.z, oo0.z); oo0.w = fmaf(h0, w2v.w, oo0.w);
                oo1.x = fmaf(h1, w2v.x, oo1.x); oo1.y = fmaf(h1, w2v.y, oo1.y);
                oo1.z = fmaf(h1, w2v.z, oo1.z); oo1.w = fmaf(h1, w2v.w, oo1.w);
                oo2.x = fmaf(h2, w2v.x, oo2.x); oo2.y = fmaf(h2, w2v.y, oo2.y);
                oo2.z = fmaf(h2, w2v.z, oo2.z); oo2.w = fmaf(h2, w2v.w, oo2.w);
                oo3.x = fmaf(h3, w2v.x, oo3.x); oo3.y = fmaf(h3, w2v.y, oo3.y);
                oo3.z = fmaf(h3, w2v.z, oo3.z); oo3.w = fmaf(h3, w2v.w, oo3.w);
            }
            // reduce over the 16 lanes sharing this M-tile's columns
#pragma unroll
            for (int d = 1; d < 16; d <<= 1) {
                oo0.x += __shfl_xor(oo0.x, d); oo0.y += __shfl_xor(oo0.y, d);
                oo0.z += __shfl_xor(oo0.z, d); oo0.w += __shfl_xor(oo0.w, d);
                oo1.x += __shfl_xor(oo1.x, d); oo1.y += __shfl_xor(oo1.y, d);
                oo1.z += __shfl_xor(oo1.z, d); oo1.w += __shfl_xor(oo1.w, d);
                oo2.x += __shfl_xor(oo2.x, d); oo2.y += __shfl_xor(oo2.y, d);
                oo2.z += __shfl_xor(oo2.z, d); oo2.w += __shfl_xor(oo2.w, d);
                oo3.x += __shfl_xor(oo3.x, d); oo3.y += __shfl_xor(oo3.y, d);
                oo3.z += __shfl_xor(oo3.z, d); oo3.w += __shfl_xor(oo3.w, d);
            }
            if (l15 == 0) {
                int ptg = base + w * 64 + mt * 16 + quad * 4;
                float4* O = (float4*)out;
                float4 r0 = {oo0.x + b2v.x, oo0.y + b2v.y, oo0.z + b2v.z, oo0.w + b2v.w};
                float4 r1 = {oo1.x + b2v.x, oo1.y + b2v.y, oo1.z + b2v.z, oo1.w + b2v.w};
                float4 r2 = {oo2.x + b2v.x, oo2.y + b2v.y, oo2.z + b2v.z, oo2.w + b2v.w};
                float4 r3 = {oo3.x + b2v.x, oo3.y + b2v.y, oo3.z + b2v.z, oo3.w + b2v.w};
                O[ptg + 0] = r0; O[ptg + 1] = r1; O[ptg + 2] = r2; O[ptg + 3] = r3;
            }
        }
    }
}

// ---------------------------------------------------------------------------
// Fallback path (ws too small): gather directly from (C,H,W) layout, VALU MLP.
// ---------------------------------------------------------------------------
__device__ __forceinline__ void mlp_and_store(
    const float feat[NC],
    const float* __restrict__ w1, const float* __restrict__ b1,
    const float* __restrict__ w2, const float* __restrict__ b2,
    float* __restrict__ out, int i)
{
    float o0 = b2[0], o1 = b2[1], o2 = b2[2], o3 = b2[3];
#pragma unroll 4
    for (int k = 0; k < NH1; ++k) {
        float hk = b1[k];
#pragma unroll
        for (int c = 0; c < NC; ++c)
            hk = fmaf(feat[c], w1[c * NH1 + k], hk);
        hk = fmaxf(hk, 0.0f);
        o0 = fmaf(hk, w2[k * 4 + 0], o0);
        o1 = fmaf(hk, w2[k * 4 + 1], o1);
        o2 = fmaf(hk, w2[k * 4 + 2], o2);
        o3 = fmaf(hk, w2[k * 4 + 3], o3);
    }
    float4 o; o.x = o0; o.y = o1; o.z = o2; o.w = o3;
    reinterpret_cast<float4*>(out)[i] = o;
}

__global__ __launch_bounds__(256) void kplane_fused_direct(
    const float* __restrict__ pts,
    const float* __restrict__ pyx, const float* __restrict__ pzx,
    const float* __restrict__ pzy,
    const float* __restrict__ w1, const float* __restrict__ b1,
    const float* __restrict__ w2, const float* __restrict__ b2,
    float* __restrict__ out, int N)
{
    int i = blockIdx.x * blockDim.x + threadIdx.x;
    if (i >= N) return;
    float px = pts[(size_t)i * 3 + 0];
    float py = pts[(size_t)i * 3 + 1];
    float pz = pts[(size_t)i * 3 + 2];

    int a00, a01, a10, a11; float aw00, aw01, aw10, aw11;
    int c00, c01, c10, c11; float cw00, cw01, cw10, cw11;
    int d00, d01, d10, d11; float dw00, dw01, dw10, dw11;
    bilin(px, py, W_YX, H_YX, a00, a01, a10, a11, aw00, aw01, aw10, aw11);
    bilin(px, pz, W_ZX, H_ZX, c00, c01, c10, c11, cw00, cw01, cw10, cw11);
    bilin(py, pz, W_ZY, H_ZY, d00, d01, d10, d11, dw00, dw01, dw10, dw11);

    float feat[NC];
#pragma unroll 4
    for (int c = 0; c < NC; ++c) {
        const float* byx = pyx + (size_t)c * HW_YX;
        const float* bzx = pzx + (size_t)c * HW_ZX;
        const float* bzy = pzy + (size_t)c * HW_ZY;
        float fyx = aw00 * byx[a00] + aw01 * byx[a01] + aw10 * byx[a10] + aw11 * byx[a11];
        float fzx = cw00 * bzx[c00] + cw01 * bzx[c01] + cw10 * bzx[c10] + cw11 * bzx[c11];
        float fzy = dw00 * bzy[d00] + dw01 * bzy[d01] + dw10 * bzy[d10] + dw11 * bzy[d11];
        feat[c] = fyx * fzx * fzy;
    }
    mlp_and_store(feat, w1, b1, w2, b2, out, i);
}

// ---------------------------------------------------------------------------
extern "C" void kernel_launch(void* const* d_in, const int* in_sizes, int n_in,
                              void* d_out, int out_size, void* d_ws, size_t ws_size,
                              hipStream_t stream)
{
    const float* pts = (const float*)d_in[0];
    const float* pyx = (const float*)d_in[1];
    const float* pzx = (const float*)d_in[2];
    const float* pzy = (const float*)d_in[3];
    const float* w1  = (const float*)d_in[4];
    const float* b1  = (const float*)d_in[5];
    const float* w2  = (const float*)d_in[6];
    const float* b2  = (const float*)d_in[7];
    float* out = (float*)d_out;

    int N = in_sizes[0] / 3;

    size_t planes_f = (size_t)(HW_YX + HW_ZX + HW_ZY) * NC;       // floats
    size_t need = planes_f * sizeof(float) + 2 * 8192 * sizeof(short);

    if (ws_size >= need && (N % 256) == 0) {
        float* tyx = (float*)d_ws;
        float* tzx = tyx + (size_t)HW_YX * NC;
        float* tzy = tzx + (size_t)HW_ZX * NC;
        short* whi = (short*)(tyx + planes_f);
        short* wlo = whi + 8192;
        kplane_transpose4<<<(HW_YX + 127) / 128, 256, 0, stream>>>(pyx, tyx, HW_YX);
        kplane_transpose4<<<(HW_ZX + 127) / 128, 256, 0, stream>>>(pzx, tzx, HW_ZX);
        kplane_transpose4<<<(HW_ZY + 127) / 128, 256, 0, stream>>>(pzy, tzy, HW_ZY);
        kplane_prep_w1<<<32, 256, 0, stream>>>(w1, whi, wlo);
        kplane_mfma<<<N / 256, 256, 0, stream>>>(pts, tyx, tzx, tzy,
                                                 whi, wlo, b1, w2, b2, out);
    } else {
        int blocks = (N + 255) / 256;
        kplane_fused_direct<<<blocks, 256, 0, stream>>>(pts, pyx, pzx, pzy,
                                                        w1, b1, w2, b2, out, N);
    }
}

// Round 3
// 645.671 us; speedup vs baseline: 2.0006x; 1.2126x over previous
//
#include <hip/hip_runtime.h>

// Problem constants (from reference setup_inputs)
#define NC    32           // channels
#define NH1   256          // hidden dim
#define W_YX  727
#define H_YX  314
#define W_ZX  727
#define H_ZX  1300
#define W_ZY  314
#define H_ZY  1300
#define HW_YX (W_YX * H_YX)   // 228278
#define HW_ZX (W_ZX * H_ZX)   // 945100
#define HW_ZY (W_ZY * H_ZY)   // 408200

#define FSTRIDE 17         // dwords per point in featS (odd => conflict-free)

typedef __attribute__((ext_vector_type(8))) short short8;   // 8 bf16 (4 VGPRs)
typedef __attribute__((ext_vector_type(4))) float f32x4;    // MFMA acc

// float -> bf16 (RNE), raw short
__device__ __forceinline__ short f2bf(float f) {
    unsigned u = __float_as_uint(f);
    unsigned r = u + 0x7fffu + ((u >> 16) & 1u);
    return (short)(r >> 16);
}

// ---------------------------------------------------------------------------
// Transpose (C=32, HW) fp32 -> (HW, C=32) bf16.
// 128hw x 32ch tile; fp32 in LDS, convert on store; 1KB-contiguous stores.
// ---------------------------------------------------------------------------
__global__ __launch_bounds__(256) void kplane_transpose_bf16(
    const float* __restrict__ src, unsigned short* __restrict__ dst, int HW)
{
    __shared__ float tile[32][129];
    int hw0 = blockIdx.x * 128;
    int tx = threadIdx.x & 31, ty = threadIdx.x >> 5;
    if (hw0 + 128 <= HW) {
#pragma unroll
        for (int i = 0; i < 4; ++i) {
            int c = ty + i * 8;
            float4 v = *(const float4*)(src + (size_t)c * HW + hw0 + tx * 4);
            tile[c][tx * 4 + 0] = v.x; tile[c][tx * 4 + 1] = v.y;
            tile[c][tx * 4 + 2] = v.z; tile[c][tx * 4 + 3] = v.w;
        }
    } else {
        for (int i = 0; i < 4; ++i) {
            int c = ty + i * 8;
            for (int e = 0; e < 4; ++e) {
                int hw = hw0 + tx * 4 + e;
                tile[c][tx * 4 + e] = (hw < HW) ? src[(size_t)c * HW + hw] : 0.0f;
            }
        }
    }
    __syncthreads();
    int c8 = threadIdx.x & 3, r0 = threadIdx.x >> 2;   // c8: channel octet
#pragma unroll
    for (int i = 0; i < 2; ++i) {
        int r = r0 + i * 64;
        int hw = hw0 + r;
        if (hw < HW) {
            uint4 o;
            unsigned* ou = (unsigned*)&o;
#pragma unroll
            for (int e = 0; e < 4; ++e) {
                unsigned lo = (unsigned)(unsigned short)f2bf(tile[c8 * 8 + 2 * e][r]);
                unsigned hi = (unsigned)(unsigned short)f2bf(tile[c8 * 8 + 2 * e + 1][r]);
                ou[e] = lo | (hi << 16);
            }
            *(uint4*)(dst + (size_t)hw * NC + c8 * 8) = o;
        }
    }
}

// ---------------------------------------------------------------------------
// w1 (32x256 fp32) -> bf16 in B-fragment order for mfma_f32_16x16x32_bf16:
// idx = (ntile*64 + lane)*8 + j holds B[k=(lane>>4)*8+j][n=ntile*16+(lane&15)]
// ---------------------------------------------------------------------------
__global__ __launch_bounds__(256) void kplane_prep_w1(
    const float* __restrict__ w1, short* __restrict__ wb)
{
    int idx = blockIdx.x * 256 + threadIdx.x;   // 0..8191
    int jj   = idx & 7;
    int lane = (idx >> 3) & 63;
    int nt   = idx >> 9;
    int n = nt * 16 + (lane & 15);
    int k = (lane >> 4) * 8 + jj;
    wb[idx] = f2bf(w1[k * NH1 + n]);
}

// ---------------------------------------------------------------------------
// Bilinear setup -> byte offsets of rows (y0,x0) and (y1,x0) + weights.
// x1 is implicitly x0+1 (the adjacent 64B row in (HW,C) bf16 layout); at the
// x-clamp edge wx==0 so the x1 half-load is multiplied by zero.
// ---------------------------------------------------------------------------
__device__ __forceinline__ void bilin2(
    float gx, float gy, int W, int H,
    unsigned& o0, unsigned& o1, float& wx, float& wy)
{
    float ix  = (gx + 1.0f) * 0.5f * (float)(W - 1);
    float iy  = (gy + 1.0f) * 0.5f * (float)(H - 1);
    float x0f = floorf(ix), y0f = floorf(iy);
    wx = ix - x0f; wy = iy - y0f;
    int x0 = (int)x0f; x0 = x0 < 0 ? 0 : (x0 > W - 1 ? W - 1 : x0);
    int y0 = (int)y0f; y0 = y0 < 0 ? 0 : (y0 > H - 1 ? H - 1 : y0);
    int y1 = y0 + 1; if (y1 > H - 1) y1 = H - 1;
    o0 = (unsigned)(y0 * W + x0) * 64u;
    o1 = (unsigned)(y1 * W + x0) * 64u;
}

// Sample 8 channels (this lane's slice) of one plane, incl. x-pair combine.
// j&4 selects x-corner; j&3 selects channel octet. After shfl_xor(4) both
// x-halves hold the full bilinear result for their 8 channels.
__device__ __forceinline__ void sample8(
    const unsigned short* __restrict__ plane,
    unsigned o0, unsigned o1, float wy, float wxv, int j, float F[8])
{
    uint4 u0 = *(const uint4*)((const char*)plane + (size_t)o0 + j * 16);
    uint4 u1 = *(const uint4*)((const char*)plane + (size_t)o1 + j * 16);
    unsigned ua[4] = {u0.x, u0.y, u0.z, u0.w};
    unsigned ub[4] = {u1.x, u1.y, u1.z, u1.w};
#pragma unroll
    for (int e = 0; e < 4; ++e) {
        float a0 = __uint_as_float(ua[e] << 16);
        float a1 = __uint_as_float(ua[e] & 0xffff0000u);
        float b0 = __uint_as_float(ub[e] << 16);
        float b1 = __uint_as_float(ub[e] & 0xffff0000u);
        F[2 * e]     = wxv * fmaf(wy, b0 - a0, a0);
        F[2 * e + 1] = wxv * fmaf(wy, b1 - a1, a1);
    }
#pragma unroll
    for (int e = 0; e < 8; ++e)
        F[e] += __shfl_xor(F[e], 4, 64);
}

// ---------------------------------------------------------------------------
// Fused: bilin (1 thread/point) -> shfl-broadcast -> cooperative bf16 gather
// (8 lanes/point, 128B x-pair loads) -> bf16 MFMA layer1 -> VALU layer2.
// Block = 256 threads = 256 points.
// ---------------------------------------------------------------------------
__global__ __launch_bounds__(256) void kplane_fused(
    const float* __restrict__ pts,
    const unsigned short* __restrict__ tyx,
    const unsigned short* __restrict__ tzx,
    const unsigned short* __restrict__ tzy,
    const short* __restrict__ w1b,
    const float* __restrict__ b1, const float* __restrict__ w2,
    const float* __restrict__ b2,
    float* __restrict__ out)
{
    __shared__ unsigned featS[256 * FSTRIDE];   // bf16 pairs, 17 dwords/point

    int t = threadIdx.x;
    int base = blockIdx.x * 256;
    int l = t & 63, j = t & 7;

    // ---- phase 0: this thread's point -> bilinear params (registers) ------
    float px = pts[(size_t)(base + t) * 3 + 0];
    float py = pts[(size_t)(base + t) * 3 + 1];
    float pz = pts[(size_t)(base + t) * 3 + 2];
    unsigned ao0, ao1, co0, co1, do0, do1;
    float awx, awy, cwx, cwy, dwx, dwy;
    bilin2(px, py, W_YX, H_YX, ao0, ao1, awx, awy);
    bilin2(px, pz, W_ZX, H_ZX, co0, co1, cwx, cwy);
    bilin2(py, pz, W_ZY, H_ZY, do0, do1, dwx, dwy);

    // ---- phase 1: cooperative gather, params via wave shfl ----------------
#pragma unroll
    for (int r = 0; r < 8; ++r) {
        int srcl = (l & 0x38) | r;      // lane (same wave) owning point p
        int p = (t & ~7) | r;           // local point id

        unsigned A0 = (unsigned)__shfl((int)ao0, srcl, 64);
        unsigned A1 = (unsigned)__shfl((int)ao1, srcl, 64);
        float AX = __shfl(awx, srcl, 64), AY = __shfl(awy, srcl, 64);
        unsigned C0 = (unsigned)__shfl((int)co0, srcl, 64);
        unsigned C1 = (unsigned)__shfl((int)co1, srcl, 64);
        float CX = __shfl(cwx, srcl, 64), CY = __shfl(cwy, srcl, 64);
        unsigned D0 = (unsigned)__shfl((int)do0, srcl, 64);
        unsigned D1 = (unsigned)__shfl((int)do1, srcl, 64);
        float DX = __shfl(dwx, srcl, 64), DY = __shfl(dwy, srcl, 64);

        float axv = (j & 4) ? AX : 1.0f - AX;
        float cxv = (j & 4) ? CX : 1.0f - CX;
        float dxv = (j & 4) ? DX : 1.0f - DX;

        float acc[8], tmp[8];
        sample8(tyx, A0, A1, AY, axv, j, acc);
        sample8(tzx, C0, C1, CY, cxv, j, tmp);
#pragma unroll
        for (int e = 0; e < 8; ++e) acc[e] *= tmp[e];
        sample8(tzy, D0, D1, DY, dxv, j, tmp);
#pragma unroll
        for (int e = 0; e < 8; ++e) acc[e] *= tmp[e];

        if (j < 4) {   // lanes 0..3 hold the final 8-ch feature slices
#pragma unroll
            for (int e = 0; e < 4; ++e) {
                unsigned lo = (unsigned)(unsigned short)f2bf(acc[2 * e]);
                unsigned hi = (unsigned)(unsigned short)f2bf(acc[2 * e + 1]);
                featS[p * FSTRIDE + j * 4 + e] = lo | (hi << 16);
            }
        }
    }
    __syncthreads();

    // ---- phase 2: MFMA layer1 + VALU layer2 -------------------------------
    {
        int w = t >> 6;
        int quad = l >> 4, l15 = l & 15;
        float4 b2v = *(const float4*)b2;
        const short8* Bw = (const short8*)w1b;

#pragma unroll
        for (int mt = 0; mt < 4; ++mt) {
            int p = w * 64 + mt * 16 + l15;
            union { unsigned u[4]; short8 s; } A;
#pragma unroll
            for (int e = 0; e < 4; ++e)
                A.u[e] = featS[p * FSTRIDE + quad * 4 + e];

            float4 oo0 = {0,0,0,0}, oo1 = {0,0,0,0}, oo2 = {0,0,0,0}, oo3 = {0,0,0,0};
#pragma unroll
            for (int nt = 0; nt < 16; ++nt) {
                short8 bh = Bw[nt * 64 + l];
                f32x4 z = {0.f, 0.f, 0.f, 0.f};
                z = __builtin_amdgcn_mfma_f32_16x16x32_bf16(A.s, bh, z, 0, 0, 0);
                float  b1v = b1[nt * 16 + l15];
                float4 w2v = ((const float4*)w2)[nt * 16 + l15];
                float h0 = fmaxf(z[0] + b1v, 0.f);
                float h1 = fmaxf(z[1] + b1v, 0.f);
                float h2 = fmaxf(z[2] + b1v, 0.f);
                float h3 = fmaxf(z[3] + b1v, 0.f);
                oo0.x = fmaf(h0, w2v.x, oo0.x); oo0.y = fmaf(h0, w2v.y, oo0.y);
                oo0.z = fmaf(h0, w2v.z, oo0.z); oo0.w = fmaf(h0, w2v.w, oo0.w);
                oo1.x = fmaf(h1, w2v.x, oo1.x); oo1.y = fmaf(h1, w2v.y, oo1.y);
                oo1.z = fmaf(h1, w2v.z, oo1.z); oo1.w = fmaf(h1, w2v.w, oo1.w);
                oo2.x = fmaf(h2, w2v.x, oo2.x); oo2.y = fmaf(h2, w2v.y, oo2.y);
                oo2.z = fmaf(h2, w2v.z, oo2.z); oo2.w = fmaf(h2, w2v.w, oo2.w);
                oo3.x = fmaf(h3, w2v.x, oo3.x); oo3.y = fmaf(h3, w2v.y, oo3.y);
                oo3.z = fmaf(h3, w2v.z, oo3.z); oo3.w = fmaf(h3, w2v.w, oo3.w);
            }
#pragma unroll
            for (int d = 1; d < 16; d <<= 1) {
                oo0.x += __shfl_xor(oo0.x, d); oo0.y += __shfl_xor(oo0.y, d);
                oo0.z += __shfl_xor(oo0.z, d); oo0.w += __shfl_xor(oo0.w, d);
                oo1.x += __shfl_xor(oo1.x, d); oo1.y += __shfl_xor(oo1.y, d);
                oo1.z += __shfl_xor(oo1.z, d); oo1.w += __shfl_xor(oo1.w, d);
                oo2.x += __shfl_xor(oo2.x, d); oo2.y += __shfl_xor(oo2.y, d);
                oo2.z += __shfl_xor(oo2.z, d); oo2.w += __shfl_xor(oo2.w, d);
                oo3.x += __shfl_xor(oo3.x, d); oo3.y += __shfl_xor(oo3.y, d);
                oo3.z += __shfl_xor(oo3.z, d); oo3.w += __shfl_xor(oo3.w, d);
            }
            if (l15 == 0) {
                int ptg = base + w * 64 + mt * 16 + quad * 4;
                float4* O = (float4*)out;
                float4 r0 = {oo0.x + b2v.x, oo0.y + b2v.y, oo0.z + b2v.z, oo0.w + b2v.w};
                float4 r1 = {oo1.x + b2v.x, oo1.y + b2v.y, oo1.z + b2v.z, oo1.w + b2v.w};
                float4 r2 = {oo2.x + b2v.x, oo2.y + b2v.y, oo2.z + b2v.z, oo2.w + b2v.w};
                float4 r3 = {oo3.x + b2v.x, oo3.y + b2v.y, oo3.z + b2v.z, oo3.w + b2v.w};
                O[ptg + 0] = r0; O[ptg + 1] = r1; O[ptg + 2] = r2; O[ptg + 3] = r3;
            }
        }
    }
}

// ---------------------------------------------------------------------------
// Fallback path (ws too small / N%256): direct (C,H,W) gather, VALU MLP.
// ---------------------------------------------------------------------------
__device__ __forceinline__ void bilin_full(
    float gx, float gy, int W, int H,
    int& o00, int& o01, int& o10, int& o11,
    float& w00, float& w01, float& w10, float& w11)
{
    float ix  = (gx + 1.0f) * 0.5f * (float)(W - 1);
    float iy  = (gy + 1.0f) * 0.5f * (float)(H - 1);
    float x0f = floorf(ix), y0f = floorf(iy);
    float wx  = ix - x0f,   wy  = iy - y0f;
    int x0 = (int)x0f; x0 = x0 < 0 ? 0 : (x0 > W - 1 ? W - 1 : x0);
    int y0 = (int)y0f; y0 = y0 < 0 ? 0 : (y0 > H - 1 ? H - 1 : y0);
    int x1 = x0 + 1; if (x1 > W - 1) x1 = W - 1;
    int y1 = y0 + 1; if (y1 > H - 1) y1 = H - 1;
    o00 = y0 * W + x0; o01 = y0 * W + x1;
    o10 = y1 * W + x0; o11 = y1 * W + x1;
    w00 = (1.0f - wx) * (1.0f - wy);
    w01 = wx * (1.0f - wy);
    w10 = (1.0f - wx) * wy;
    w11 = wx * wy;
}

__global__ __launch_bounds__(256) void kplane_fused_direct(
    const float* __restrict__ pts,
    const float* __restrict__ pyx, const float* __restrict__ pzx,
    const float* __restrict__ pzy,
    const float* __restrict__ w1, const float* __restrict__ b1,
    const float* __restrict__ w2, const float* __restrict__ b2,
    float* __restrict__ out, int N)
{
    int i = blockIdx.x * blockDim.x + threadIdx.x;
    if (i >= N) return;
    float px = pts[(size_t)i * 3 + 0];
    float py = pts[(size_t)i * 3 + 1];
    float pz = pts[(size_t)i * 3 + 2];

    int a00, a01, a10, a11; float aw00, aw01, aw10, aw11;
    int c00, c01, c10, c11; float cw00, cw01, cw10, cw11;
    int d00, d01, d10, d11; float dw00, dw01, dw10, dw11;
    bilin_full(px, py, W_YX, H_YX, a00, a01, a10, a11, aw00, aw01, aw10, aw11);
    bilin_full(px, pz, W_ZX, H_ZX, c00, c01, c10, c11, cw00, cw01, cw10, cw11);
    bilin_full(py, pz, W_ZY, H_ZY, d00, d01, d10, d11, dw00, dw01, dw10, dw11);

    float feat[NC];
#pragma unroll 4
    for (int c = 0; c < NC; ++c) {
        const float* byx = pyx + (size_t)c * HW_YX;
        const float* bzx = pzx + (size_t)c * HW_ZX;
        const float* bzy = pzy + (size_t)c * HW_ZY;
        float fyx = aw00 * byx[a00] + aw01 * byx[a01] + aw10 * byx[a10] + aw11 * byx[a11];
        float fzx = cw00 * bzx[c00] + cw01 * bzx[c01] + cw10 * bzx[c10] + cw11 * bzx[c11];
        float fzy = dw00 * bzy[d00] + dw01 * bzy[d01] + dw10 * bzy[d10] + dw11 * bzy[d11];
        feat[c] = fyx * fzx * fzy;
    }
    float o0 = b2[0], o1 = b2[1], o2 = b2[2], o3 = b2[3];
#pragma unroll 4
    for (int k = 0; k < NH1; ++k) {
        float hk = b1[k];
#pragma unroll
        for (int c = 0; c < NC; ++c)
            hk = fmaf(feat[c], w1[c * NH1 + k], hk);
        hk = fmaxf(hk, 0.0f);
        o0 = fmaf(hk, w2[k * 4 + 0], o0);
        o1 = fmaf(hk, w2[k * 4 + 1], o1);
        o2 = fmaf(hk, w2[k * 4 + 2], o2);
        o3 = fmaf(hk, w2[k * 4 + 3], o3);
    }
    float4 o; o.x = o0; o.y = o1; o.z = o2; o.w = o3;
    reinterpret_cast<float4*>(out)[i] = o;
}

// ---------------------------------------------------------------------------
extern "C" void kernel_launch(void* const* d_in, const int* in_sizes, int n_in,
                              void* d_out, int out_size, void* d_ws, size_t ws_size,
                              hipStream_t stream)
{
    const float* pts = (const float*)d_in[0];
    const float* pyx = (const float*)d_in[1];
    const float* pzx = (const float*)d_in[2];
    const float* pzy = (const float*)d_in[3];
    const float* w1  = (const float*)d_in[4];
    const float* b1  = (const float*)d_in[5];
    const float* w2  = (const float*)d_in[6];
    const float* b2  = (const float*)d_in[7];
    float* out = (float*)d_out;

    int N = in_sizes[0] / 3;

    size_t planes_e = (size_t)(HW_YX + HW_ZX + HW_ZY) * NC;  // bf16 elements
    size_t need = planes_e * sizeof(short) + 8192 * sizeof(short) + 256; // ~101 MB

    if (ws_size >= need && (N % 256) == 0) {
        unsigned short* tyx = (unsigned short*)d_ws;
        unsigned short* tzx = tyx + (size_t)HW_YX * NC;
        unsigned short* tzy = tzx + (size_t)HW_ZX * NC;
        short* w1b = (short*)(tzy + (size_t)HW_ZY * NC);
        kplane_transpose_bf16<<<(HW_YX + 127) / 128, 256, 0, stream>>>(pyx, tyx, HW_YX);
        kplane_transpose_bf16<<<(HW_ZX + 127) / 128, 256, 0, stream>>>(pzx, tzx, HW_ZX);
        kplane_transpose_bf16<<<(HW_ZY + 127) / 128, 256, 0, stream>>>(pzy, tzy, HW_ZY);
        kplane_prep_w1<<<32, 256, 0, stream>>>(w1, w1b);
        kplane_fused<<<N / 256, 256, 0, stream>>>(pts, tyx, tzx, tzy,
                                                  w1b, b1, w2, b2, out);
    } else {
        int blocks = (N + 255) / 256;
        kplane_fused_direct<<<blocks, 256, 0, stream>>>(pts, pyx, pzx, pzy,
                                                        w1, b1, w2, b2, out, N);
    }
}

// Round 4
// 602.015 us; speedup vs baseline: 2.1457x; 1.0725x over previous
//
#include <hip/hip_runtime.h>
#include <hip/hip_fp16.h>
#include <hip/hip_bf16.h>

// Problem constants (from reference setup_inputs)
#define NC    32           // channels
#define NH1   256          // hidden dim
#define W_YX  727
#define H_YX  314
#define W_ZX  727
#define H_ZX  1300
#define W_ZY  314
#define H_ZY  1300
#define HW_YX (W_YX * H_YX)   // 228278
#define HW_ZX (W_ZX * H_ZX)   // 945100
#define HW_ZY (W_ZY * H_ZY)   // 408200

#define PSTRIDE 12         // dwords per point in parS  (12p%32: 2-way = free)
#define FSTRIDE 20         // dwords per point in featS (20p%32: 2-way, 16B-aligned)

typedef __attribute__((ext_vector_type(8))) short short8;   // 8 bf16 (4 VGPRs)
typedef __attribute__((ext_vector_type(4))) float f32x4;    // MFMA acc

// float -> bf16 (RNE), raw short (cold-path prep kernels)
__device__ __forceinline__ short f2bf(float f) {
    unsigned u = __float_as_uint(f);
    unsigned r = u + 0x7fffu + ((u >> 16) & 1u);
    return (short)(r >> 16);
}
// pack two floats -> bf16 pair (RNE; v_cvt_pk_bf16_f32 on gfx950)
__device__ __forceinline__ unsigned pk2(float a, float b) {
    union { __hip_bfloat162 h; unsigned u; } c;
    c.h = __float22bfloat162_rn(make_float2(a, b));
    return c.u;
}

// ---------------------------------------------------------------------------
// Transpose (C=32, HW) fp32 -> (HW, C=32) bf16.
// ---------------------------------------------------------------------------
__global__ __launch_bounds__(256) void kplane_transpose_bf16(
    const float* __restrict__ src, unsigned short* __restrict__ dst, int HW)
{
    __shared__ float tile[32][129];
    int hw0 = blockIdx.x * 128;
    int tx = threadIdx.x & 31, ty = threadIdx.x >> 5;
    if (hw0 + 128 <= HW) {
#pragma unroll
        for (int i = 0; i < 4; ++i) {
            int c = ty + i * 8;
            float4 v = *(const float4*)(src + (size_t)c * HW + hw0 + tx * 4);
            tile[c][tx * 4 + 0] = v.x; tile[c][tx * 4 + 1] = v.y;
            tile[c][tx * 4 + 2] = v.z; tile[c][tx * 4 + 3] = v.w;
        }
    } else {
        for (int i = 0; i < 4; ++i) {
            int c = ty + i * 8;
            for (int e = 0; e < 4; ++e) {
                int hw = hw0 + tx * 4 + e;
                tile[c][tx * 4 + e] = (hw < HW) ? src[(size_t)c * HW + hw] : 0.0f;
            }
        }
    }
    __syncthreads();
    int c8 = threadIdx.x & 3, r0 = threadIdx.x >> 2;
#pragma unroll
    for (int i = 0; i < 2; ++i) {
        int r = r0 + i * 64;
        int hw = hw0 + r;
        if (hw < HW) {
            uint4 o;
            unsigned* ou = (unsigned*)&o;
#pragma unroll
            for (int e = 0; e < 4; ++e)
                ou[e] = pk2(tile[c8 * 8 + 2 * e][r], tile[c8 * 8 + 2 * e + 1][r]);
            *(uint4*)(dst + (size_t)hw * NC + c8 * 8) = o;
        }
    }
}

// ---------------------------------------------------------------------------
// w1 (32x256) -> bf16 A-fragment order for MFMA1 (A = w1^T, m=hidden, k=ch):
// w1a[(nt*64+lane)*8+j] = w1[ch=(lane>>4)*8+j][hid=nt*16+(lane&15)]
// ---------------------------------------------------------------------------
__global__ __launch_bounds__(256) void kplane_prep_w1a(
    const float* __restrict__ w1, short* __restrict__ w1a)
{
    int idx = blockIdx.x * 256 + threadIdx.x;   // 0..8191
    int j    = idx & 7;
    int lane = (idx >> 3) & 63;
    int nt   = idx >> 9;
    int ch  = (lane >> 4) * 8 + j;
    int hid = nt * 16 + (lane & 15);
    w1a[idx] = f2bf(w1[ch * NH1 + hid]);
}

// ---------------------------------------------------------------------------
// w2 (256x4) -> bf16 A-fragment order for MFMA2 (A = w2^T, m=o, k=hidden),
// hidden permutation matched to MFMA1's C-layout-as-B2 trick:
// k slot (kk,quad,j) <-> hidden = (2kk+(j>=4))*16 + quad*4 + (j&3)
// ---------------------------------------------------------------------------
__global__ __launch_bounds__(256) void kplane_prep_w2a(
    const float* __restrict__ w2, short* __restrict__ w2a)
{
    int idx = blockIdx.x * 256 + threadIdx.x;   // 0..4095
    int j    = idx & 7;
    int lane = (idx >> 3) & 63;
    int kk   = idx >> 9;
    int o    = lane & 15;
    int quad = lane >> 4;
    int hid  = (2 * kk + (j >> 2)) * 16 + quad * 4 + (j & 3);
    float v  = (o < 4) ? w2[hid * 4 + o] : 0.0f;
    w2a[idx] = f2bf(v);
}

// ---------------------------------------------------------------------------
// Bilinear setup: byte offsets of the two y-rows at x0 (x1 = +64B implicit;
// at the x-clamp edge wx==0 so the x1 half is weighted to zero).
// ---------------------------------------------------------------------------
__device__ __forceinline__ void bilin3(
    float gx, float gy, int W, int H,
    unsigned& o0, unsigned& o1, float& wx, float& wy)
{
    float ix  = (gx + 1.0f) * 0.5f * (float)(W - 1);
    float iy  = (gy + 1.0f) * 0.5f * (float)(H - 1);
    float x0f = floorf(ix), y0f = floorf(iy);
    wx = ix - x0f; wy = iy - y0f;
    int x0 = (int)x0f; x0 = x0 < 0 ? 0 : (x0 > W - 1 ? W - 1 : x0);
    int y0 = (int)y0f; y0 = y0 < 0 ? 0 : (y0 > H - 1 ? H - 1 : y0);
    int y1 = y0 + 1; if (y1 > H - 1) y1 = H - 1;
    o0 = (unsigned)(y0 * W + x0) * 64u;
    o1 = (unsigned)(y1 * W + x0) * 64u;
}

// Bilinear-combine 4 corner chunks (8 channels) fully in-lane.
template <bool FIRST>
__device__ __forceinline__ void corner4(
    const uint4& A, const uint4& B, const uint4& C, const uint4& D,
    float wx, float wy, float F[8])
{
    float w00 = (1.0f - wx) * (1.0f - wy);
    float w01 = wx * (1.0f - wy);
    float w10 = (1.0f - wx) * wy;
    float w11 = wx * wy;
    const unsigned* ua = &A.x; const unsigned* ub = &B.x;
    const unsigned* uc = &C.x; const unsigned* ud = &D.x;
#pragma unroll
    for (int e = 0; e < 4; ++e) {
        float a0 = __uint_as_float(ua[e] << 16);
        float a1 = __uint_as_float(ua[e] & 0xffff0000u);
        float b0 = __uint_as_float(ub[e] << 16);
        float b1 = __uint_as_float(ub[e] & 0xffff0000u);
        float c0 = __uint_as_float(uc[e] << 16);
        float c1 = __uint_as_float(uc[e] & 0xffff0000u);
        float d0 = __uint_as_float(ud[e] << 16);
        float d1 = __uint_as_float(ud[e] & 0xffff0000u);
        float v0 = w00 * a0; v0 = fmaf(w01, b0, v0);
        v0 = fmaf(w10, c0, v0); v0 = fmaf(w11, d0, v0);
        float v1 = w00 * a1; v1 = fmaf(w01, b1, v1);
        v1 = fmaf(w10, c1, v1); v1 = fmaf(w11, d1, v1);
        if (FIRST) { F[2 * e] = v0; F[2 * e + 1] = v1; }
        else       { F[2 * e] *= v0; F[2 * e + 1] *= v1; }
    }
}

// ---------------------------------------------------------------------------
// Fused kernel. Block = 256 threads = 256 points.
// Phase 0: 1 thread/point computes bilinear params -> LDS (12 dwords/pt).
// Phase 1: 4 lanes/point, 12 in-lane 16B corner loads, zero shuffles,
//          features packed bf16 -> LDS.
// Phase 2: MFMA1 (A=w1^T) -> relu+pack -> MFMA2 (A=w2^T) with a hidden
//          permutation that makes C1-layout == B2-layout. No reductions.
// ---------------------------------------------------------------------------
__global__ __launch_bounds__(256) void kplane_fused(
    const float* __restrict__ pts,
    const unsigned short* __restrict__ tyx,
    const unsigned short* __restrict__ tzx,
    const unsigned short* __restrict__ tzy,
    const short* __restrict__ w1a, const short* __restrict__ w2a,
    const float* __restrict__ b1, const float* __restrict__ b2,
    float* __restrict__ out)
{
    __shared__ unsigned parS[256 * PSTRIDE];    // 12 KB
    __shared__ unsigned featS[256 * FSTRIDE];   // 20 KB

    int t = threadIdx.x;
    int base = blockIdx.x * 256;

    // ---- phase 0: bilinear params for point `t` ---------------------------
    {
        float px = pts[(size_t)(base + t) * 3 + 0];
        float py = pts[(size_t)(base + t) * 3 + 1];
        float pz = pts[(size_t)(base + t) * 3 + 2];
        unsigned a0, a1, c0, c1, d0, d1;
        float awx, awy, cwx, cwy, dwx, dwy;
        bilin3(px, py, W_YX, H_YX, a0, a1, awx, awy);
        bilin3(px, pz, W_ZX, H_ZX, c0, c1, cwx, cwy);
        bilin3(py, pz, W_ZY, H_ZY, d0, d1, dwx, dwy);
        uint4* P = (uint4*)&parS[t * PSTRIDE];
        uint4 P0 = {a0, a1, c0, c1};
        uint4 P1 = {d0, d1, __float_as_uint(awx), __float_as_uint(awy)};
        uint4 P2 = {__float_as_uint(cwx), __float_as_uint(cwy),
                    __float_as_uint(dwx), __float_as_uint(dwy)};
        P[0] = P0; P[1] = P1; P[2] = P2;
    }
    __syncthreads();

    // ---- phase 1: gather, 4 lanes/point -----------------------------------
    {
        int q = t >> 2, j = t & 3;
        int jx16 = j * 16;
        const char* Byx = (const char*)tyx;
        const char* Bzx = (const char*)tzx;
        const char* Bzy = (const char*)tzy;
#pragma unroll
        for (int r = 0; r < 4; ++r) {
            int p = r * 64 + q;
            const uint4* P = (const uint4*)&parS[p * PSTRIDE];
            uint4 P0 = P[0], P1 = P[1], P2 = P[2];
            float awx = __uint_as_float(P1.z), awy = __uint_as_float(P1.w);
            float cwx = __uint_as_float(P2.x), cwy = __uint_as_float(P2.y);
            float dwx = __uint_as_float(P2.z), dwy = __uint_as_float(P2.w);

            // 12 independent 16B loads (all issued before use)
            uint4 La = *(const uint4*)(Byx + P0.x + jx16);
            uint4 Lb = *(const uint4*)(Byx + P0.x + 64 + jx16);
            uint4 Lc = *(const uint4*)(Byx + P0.y + jx16);
            uint4 Ld = *(const uint4*)(Byx + P0.y + 64 + jx16);
            uint4 Ma = *(const uint4*)(Bzx + P0.z + jx16);
            uint4 Mb = *(const uint4*)(Bzx + P0.z + 64 + jx16);
            uint4 Mc = *(const uint4*)(Bzx + P0.w + jx16);
            uint4 Md = *(const uint4*)(Bzx + P0.w + 64 + jx16);
            uint4 Na = *(const uint4*)(Bzy + P1.x + jx16);
            uint4 Nb = *(const uint4*)(Bzy + P1.x + 64 + jx16);
            uint4 Nc = *(const uint4*)(Bzy + P1.y + jx16);
            uint4 Nd = *(const uint4*)(Bzy + P1.y + 64 + jx16);

            float F[8];
            corner4<true >(La, Lb, Lc, Ld, awx, awy, F);
            corner4<false>(Ma, Mb, Mc, Md, cwx, cwy, F);
            corner4<false>(Na, Nb, Nc, Nd, dwx, dwy, F);

            uint4 o;
            o.x = pk2(F[0], F[1]); o.y = pk2(F[2], F[3]);
            o.z = pk2(F[4], F[5]); o.w = pk2(F[6], F[7]);
            *(uint4*)&featS[p * FSTRIDE + j * 4] = o;
        }
    }
    __syncthreads();

    // ---- phase 2: MFMA1 -> relu/pack -> MFMA2 -----------------------------
    {
        int w = t >> 6, lane = t & 63;
        int quad = lane >> 4, l15 = lane & 15;
        const short8* W1A = (const short8*)w1a;
        const short8* W2A = (const short8*)w2a;
        const float4* B1v = (const float4*)b1;
        float b20 = b2[0], b21 = b2[1], b22 = b2[2], b23 = b2[3];

#pragma unroll
        for (int mt = 0; mt < 4; ++mt) {
            int pt = w * 64 + mt * 16 + l15;
            union { uint4 v; short8 s; } bf;
            bf.v = *(const uint4*)&featS[pt * FSTRIDE + quad * 4];

            f32x4 acc = {0.f, 0.f, 0.f, 0.f};
#pragma unroll
            for (int kk = 0; kk < 8; ++kk) {
                float4 be = B1v[(2 * kk) * 4 + quad];
                float4 bo = B1v[(2 * kk + 1) * 4 + quad];
                f32x4 ze = {be.x, be.y, be.z, be.w};
                f32x4 zo = {bo.x, bo.y, bo.z, bo.w};
                ze = __builtin_amdgcn_mfma_f32_16x16x32_bf16(
                         W1A[(2 * kk) * 64 + lane], bf.s, ze, 0, 0, 0);
                zo = __builtin_amdgcn_mfma_f32_16x16x32_bf16(
                         W1A[(2 * kk + 1) * 64 + lane], bf.s, zo, 0, 0, 0);
                union { unsigned u[4]; short8 s; } hb;
                hb.u[0] = pk2(fmaxf(ze[0], 0.f), fmaxf(ze[1], 0.f));
                hb.u[1] = pk2(fmaxf(ze[2], 0.f), fmaxf(ze[3], 0.f));
                hb.u[2] = pk2(fmaxf(zo[0], 0.f), fmaxf(zo[1], 0.f));
                hb.u[3] = pk2(fmaxf(zo[2], 0.f), fmaxf(zo[3], 0.f));
                acc = __builtin_amdgcn_mfma_f32_16x16x32_bf16(
                          W2A[kk * 64 + lane], hb.s, acc, 0, 0, 0);
            }
            if (quad == 0) {
                float4 o = {acc[0] + b20, acc[1] + b21, acc[2] + b22, acc[3] + b23};
                ((float4*)out)[base + w * 64 + mt * 16 + l15] = o;
            }
        }
    }
}

// ---------------------------------------------------------------------------
// Fallback path (ws too small / N%256): direct (C,H,W) gather, VALU MLP.
// ---------------------------------------------------------------------------
__device__ __forceinline__ void bilin_full(
    float gx, float gy, int W, int H,
    int& o00, int& o01, int& o10, int& o11,
    float& w00, float& w01, float& w10, float& w11)
{
    float ix  = (gx + 1.0f) * 0.5f * (float)(W - 1);
    float iy  = (gy + 1.0f) * 0.5f * (float)(H - 1);
    float x0f = floorf(ix), y0f = floorf(iy);
    float wx  = ix - x0f,   wy  = iy - y0f;
    int x0 = (int)x0f; x0 = x0 < 0 ? 0 : (x0 > W - 1 ? W - 1 : x0);
    int y0 = (int)y0f; y0 = y0 < 0 ? 0 : (y0 > H - 1 ? H - 1 : y0);
    int x1 = x0 + 1; if (x1 > W - 1) x1 = W - 1;
    int y1 = y0 + 1; if (y1 > H - 1) y1 = H - 1;
    o00 = y0 * W + x0; o01 = y0 * W + x1;
    o10 = y1 * W + x0; o11 = y1 * W + x1;
    w00 = (1.0f - wx) * (1.0f - wy);
    w01 = wx * (1.0f - wy);
    w10 = (1.0f - wx) * wy;
    w11 = wx * wy;
}

__global__ __launch_bounds__(256) void kplane_fused_direct(
    const float* __restrict__ pts,
    const float* __restrict__ pyx, const float* __restrict__ pzx,
    const float* __restrict__ pzy,
    const float* __restrict__ w1, const float* __restrict__ b1,
    const float* __restrict__ w2, const float* __restrict__ b2,
    float* __restrict__ out, int N)
{
    int i = blockIdx.x * blockDim.x + threadIdx.x;
    if (i >= N) return;
    float px = pts[(size_t)i * 3 + 0];
    float py = pts[(size_t)i * 3 + 1];
    float pz = pts[(size_t)i * 3 + 2];

    int a00, a01, a10, a11; float aw00, aw01, aw10, aw11;
    int c00, c01, c10, c11; float cw00, cw01, cw10, cw11;
    int d00, d01, d10, d11; float dw00, dw01, dw10, dw11;
    bilin_full(px, py, W_YX, H_YX, a00, a01, a10, a11, aw00, aw01, aw10, aw11);
    bilin_full(px, pz, W_ZX, H_ZX, c00, c01, c10, c11, cw00, cw01, cw10, cw11);
    bilin_full(py, pz, W_ZY, H_ZY, d00, d01, d10, d11, dw00, dw01, dw10, dw11);

    float feat[NC];
#pragma unroll 4
    for (int c = 0; c < NC; ++c) {
        const float* byx = pyx + (size_t)c * HW_YX;
        const float* bzx = pzx + (size_t)c * HW_ZX;
        const float* bzy = pzy + (size_t)c * HW_ZY;
        float fyx = aw00 * byx[a00] + aw01 * byx[a01] + aw10 * byx[a10] + aw11 * byx[a11];
        float fzx = cw00 * bzx[c00] + cw01 * bzx[c01] + cw10 * bzx[c10] + cw11 * bzx[c11];
        float fzy = dw00 * bzy[d00] + dw01 * bzy[d01] + dw10 * bzy[d10] + dw11 * bzy[d11];
        feat[c] = fyx * fzx * fzy;
    }
    float o0 = b2[0], o1 = b2[1], o2 = b2[2], o3 = b2[3];
#pragma unroll 4
    for (int k = 0; k < NH1; ++k) {
        float hk = b1[k];
#pragma unroll
        for (int c = 0; c < NC; ++c)
            hk = fmaf(feat[c], w1[c * NH1 + k], hk);
        hk = fmaxf(hk, 0.0f);
        o0 = fmaf(hk, w2[k * 4 + 0], o0);
        o1 = fmaf(hk, w2[k * 4 + 1], o1);
        o2 = fmaf(hk, w2[k * 4 + 2], o2);
        o3 = fmaf(hk, w2[k * 4 + 3], o3);
    }
    float4 o; o.x = o0; o.y = o1; o.z = o2; o.w = o3;
    reinterpret_cast<float4*>(out)[i] = o;
}

// ---------------------------------------------------------------------------
extern "C" void kernel_launch(void* const* d_in, const int* in_sizes, int n_in,
                              void* d_out, int out_size, void* d_ws, size_t ws_size,
                              hipStream_t stream)
{
    const float* pts = (const float*)d_in[0];
    const float* pyx = (const float*)d_in[1];
    const float* pzx = (const float*)d_in[2];
    const float* pzy = (const float*)d_in[3];
    const float* w1  = (const float*)d_in[4];
    const float* b1  = (const float*)d_in[5];
    const float* w2  = (const float*)d_in[6];
    const float* b2  = (const float*)d_in[7];
    float* out = (float*)d_out;

    int N = in_sizes[0] / 3;

    size_t planes_e = (size_t)(HW_YX + HW_ZX + HW_ZY) * NC;  // bf16 elements
    size_t need = (planes_e + 8192 + 4096) * sizeof(short) + 256;

    if (ws_size >= need && (N % 256) == 0) {
        unsigned short* tyx = (unsigned short*)d_ws;
        unsigned short* tzx = tyx + (size_t)HW_YX * NC;
        unsigned short* tzy = tzx + (size_t)HW_ZX * NC;
        short* w1a = (short*)(tzy + (size_t)HW_ZY * NC);
        short* w2a = w1a + 8192;
        kplane_transpose_bf16<<<(HW_YX + 127) / 128, 256, 0, stream>>>(pyx, tyx, HW_YX);
        kplane_transpose_bf16<<<(HW_ZX + 127) / 128, 256, 0, stream>>>(pzx, tzx, HW_ZX);
        kplane_transpose_bf16<<<(HW_ZY + 127) / 128, 256, 0, stream>>>(pzy, tzy, HW_ZY);
        kplane_prep_w1a<<<32, 256, 0, stream>>>(w1, w1a);
        kplane_prep_w2a<<<16, 256, 0, stream>>>(w2, w2a);
        kplane_fused<<<N / 256, 256, 0, stream>>>(pts, tyx, tzx, tzy,
                                                  w1a, w2a, b1, b2, out);
    } else {
        int blocks = (N + 255) / 256;
        kplane_fused_direct<<<blocks, 256, 0, stream>>>(pts, pyx, pzx, pzy,
                                                        w1, b1, w2, b2, out, N);
    }
}